// Round 1
// baseline (201.155 us; speedup 1.0000x reference)
//
#include <hip/hip_runtime.h>
#include <hip/hip_bf16.h>
#include <stdint.h>

#define S_LEN 2048
#define D_DIM 128
#define QT 128          // q rows per block
#define KT 64           // k rows per tile
#define KS 136          // K lds row stride (128+8), 272B: 16B-aligned, banks +4/row
#define VS 72           // VT lds row stride (64+8), 144B: 16B-aligned, banks +4/row
#define PS 72           // P lds row stride

typedef float  f32x4  __attribute__((ext_vector_type(4)));
typedef short  bf16x8 __attribute__((ext_vector_type(8)));
typedef short  bf16x4 __attribute__((ext_vector_type(4)));

__device__ __forceinline__ short f2bf(float f) {
    union { float f; uint32_t u; } x; x.f = f;
    uint32_t r = x.u + 0x7fffu + ((x.u >> 16) & 1u);  // RNE
    return (short)(r >> 16);
}

__global__ __launch_bounds__(256, 2)
void relu2_attn_kernel(const float* __restrict__ q,
                       const float* __restrict__ k,
                       const float* __restrict__ v,
                       const float* __restrict__ scale_p,
                       float* __restrict__ out) {
    __shared__ short Klds[KT][KS];        // 17408 B
    __shared__ short VTlds[D_DIM][VS];    // 18432 B  (V transposed: VT[d][k])
    __shared__ short Plds[QT][PS];        // 18432 B  (wave-private row bands)

    const int tid  = threadIdx.x;
    const int wave = tid >> 6;
    const int lane = tid & 63;
    const int l15  = lane & 15;
    const int lg   = lane >> 4;           // 0..3

    const int bid = blockIdx.x;
    const int bh  = bid & 31;             // B*H = 32 (minor: same-bh blocks -> same XCD)
    const int qt  = bid >> 5;             // 0..15
    const int q0  = qt * QT;

    const float* qb = q + (size_t)bh * S_LEN * D_DIM;
    const float* kb = k + (size_t)bh * S_LEN * D_DIM;
    const float* vb = v + (size_t)bh * S_LEN * D_DIM;
    float*       ob = out + (size_t)bh * S_LEN * D_DIM;

    const float scale = scale_p[0];

    // ---- Q fragments hoisted to registers: qa[qf][dk]
    // A-frag layout: lane holds A[l&15][(l>>4)*8 + e], e=0..7
    bf16x8 qa[2][4];
    {
        const int qrow = q0 + wave * 32;
        #pragma unroll
        for (int qf = 0; qf < 2; ++qf) {
            const float* qp = qb + (size_t)(qrow + qf*16 + l15) * D_DIM + lg * 8;
            #pragma unroll
            for (int dk = 0; dk < 4; ++dk) {
                f32x4 a = *(const f32x4*)(qp + dk*32);
                f32x4 b = *(const f32x4*)(qp + dk*32 + 4);
                bf16x8 t;
                t[0]=f2bf(a[0]); t[1]=f2bf(a[1]); t[2]=f2bf(a[2]); t[3]=f2bf(a[3]);
                t[4]=f2bf(b[0]); t[5]=f2bf(b[1]); t[6]=f2bf(b[2]); t[7]=f2bf(b[3]);
                qa[qf][dk] = t;
            }
        }
    }

    f32x4 oacc[2][8];
    #pragma unroll
    for (int i = 0; i < 2; ++i)
        #pragma unroll
        for (int j = 0; j < 8; ++j)
            oacc[i][j] = f32x4{0.f, 0.f, 0.f, 0.f};

    for (int kt = 0; kt < S_LEN / KT; ++kt) {
        const int k0 = kt * KT;

        // ---- stage K tile row-major (bf16), coalesced float4 loads
        {
            const int r = tid >> 5;       // 0..7
            const int c = tid & 31;       // float4 chunk
            #pragma unroll
            for (int p = 0; p < 8; ++p) {
                const int row = p*8 + r;
                f32x4 a = *(const f32x4*)(kb + (size_t)(k0+row)*D_DIM + c*4);
                bf16x4 t; t[0]=f2bf(a[0]); t[1]=f2bf(a[1]); t[2]=f2bf(a[2]); t[3]=f2bf(a[3]);
                *(bf16x4*)&Klds[row][c*4] = t;
            }
        }
        // ---- stage V transposed: thread reads a 4-row column strip (coalesced
        //      across lanes), writes packed bf16x4 into a VT row.
        {
            const int d  = tid & 127;
            const int kq = (tid >> 7) * 4;          // 0 or 4
            #pragma unroll
            for (int p = 0; p < 8; ++p) {
                const int kkb = p*8 + kq;           // 0,4,...,60
                const float* vp = vb + (size_t)(k0+kkb)*D_DIM + d;
                bf16x4 t;
                t[0]=f2bf(vp[0*D_DIM]); t[1]=f2bf(vp[1*D_DIM]);
                t[2]=f2bf(vp[2*D_DIM]); t[3]=f2bf(vp[3*D_DIM]);
                *(bf16x4*)&VTlds[d][kkb] = t;
            }
        }
        __syncthreads();

        // ---- S = Q K^T  (per wave: 32q x 64k as 2x4 16x16 fragments)
        f32x4 sacc[2][4];
        #pragma unroll
        for (int qf = 0; qf < 2; ++qf)
            #pragma unroll
            for (int kf = 0; kf < 4; ++kf)
                sacc[qf][kf] = f32x4{0.f, 0.f, 0.f, 0.f};

        #pragma unroll
        for (int dk = 0; dk < 4; ++dk) {
            #pragma unroll
            for (int kf = 0; kf < 4; ++kf) {
                // B-frag: lane holds K[kf*16 + (l&15)][dk*32 + (l>>4)*8 + e]
                bf16x8 bf = *(const bf16x8*)&Klds[kf*16 + l15][dk*32 + lg*8];
                #pragma unroll
                for (int qf = 0; qf < 2; ++qf)
                    sacc[qf][kf] = __builtin_amdgcn_mfma_f32_16x16x32_bf16(
                        qa[qf][dk], bf, sacc[qf][kf], 0, 0, 0);
            }
        }

        // ---- P = relu(S*scale)^2 -> bf16 -> wave-private LDS rows
        #pragma unroll
        for (int qf = 0; qf < 2; ++qf) {
            #pragma unroll
            for (int kf = 0; kf < 4; ++kf) {
                f32x4 sv = sacc[qf][kf];
                #pragma unroll
                for (int e = 0; e < 4; ++e) {
                    float x = sv[e] * scale;
                    float r = fmaxf(x, 0.f);
                    Plds[wave*32 + qf*16 + lg*4 + e][kf*16 + l15] = f2bf(r * r);
                }
            }
        }
        // (no barrier: P rows are wave-private; compiler orders LDS w->r)

        // ---- O += P V   (per wave: 32q x 128d as 2x8 fragments, k in 2 steps)
        #pragma unroll
        for (int ks = 0; ks < 2; ++ks) {
            bf16x8 pa[2];
            #pragma unroll
            for (int qf = 0; qf < 2; ++qf)
                pa[qf] = *(const bf16x8*)&Plds[wave*32 + qf*16 + l15][ks*32 + lg*8];
            #pragma unroll
            for (int df = 0; df < 8; ++df) {
                bf16x8 vf = *(const bf16x8*)&VTlds[df*16 + l15][ks*32 + lg*8];
                #pragma unroll
                for (int qf = 0; qf < 2; ++qf)
                    oacc[qf][df] = __builtin_amdgcn_mfma_f32_16x16x32_bf16(
                        pa[qf], vf, oacc[qf][df], 0, 0, 0);
            }
        }
        __syncthreads();   // protect Klds/VTlds before next stage
    }

    // ---- epilogue: O fp32 scalar stores (D-layout: row=(l>>4)*4+e, col=l&15)
    #pragma unroll
    for (int qf = 0; qf < 2; ++qf) {
        #pragma unroll
        for (int df = 0; df < 8; ++df) {
            f32x4 o = oacc[qf][df];
            const int row = q0 + wave*32 + qf*16 + lg*4;
            float* op = ob + (size_t)row * D_DIM + df*16 + l15;
            op[0*D_DIM] = o[0];
            op[1*D_DIM] = o[1];
            op[2*D_DIM] = o[2];
            op[3*D_DIM] = o[3];
        }
    }
}

extern "C" void kernel_launch(void* const* d_in, const int* in_sizes, int n_in,
                              void* d_out, int out_size, void* d_ws, size_t ws_size,
                              hipStream_t stream) {
    const float* q = (const float*)d_in[0];
    const float* k = (const float*)d_in[1];
    const float* v = (const float*)d_in[2];
    const float* scale = (const float*)d_in[3];
    float* out = (float*)d_out;

    const int blocks = (2 * 16) * (S_LEN / QT);   // 32 bh * 16 q-tiles = 512
    relu2_attn_kernel<<<dim3(blocks), dim3(256), 0, stream>>>(q, k, v, scale, out);
}

// Round 2
// 103.272 us; speedup vs baseline: 1.9478x; 1.9478x over previous
//
#include <hip/hip_runtime.h>
#include <hip/hip_bf16.h>
#include <stdint.h>

#define S_LEN 2048
#define D_DIM 128
#define QT 128          // q rows per block
#define KT 64           // k rows per tile
#define NT (S_LEN/KT)   // 32 tiles
#define KS 136          // K lds row stride (shorts): 272B, 16B-aligned, +4 banks/row
#define VS 72           // VT lds row stride: 144B, 16B-aligned
#define PS 72           // P lds row stride

typedef float  f32x4  __attribute__((ext_vector_type(4)));
typedef short  bf16x8 __attribute__((ext_vector_type(8)));

__device__ __forceinline__ short f2bf(float f) {
    return __builtin_bit_cast(short, __float2bfloat16(f));
}

__global__ __launch_bounds__(256, 2)
void relu2_attn_kernel(const float* __restrict__ q,
                       const float* __restrict__ k,
                       const float* __restrict__ v,
                       const float* __restrict__ scale_p,
                       float* __restrict__ out) {
    __shared__ short Klds[KT][KS];        // 17.4 KB
    __shared__ short VTlds[D_DIM][VS];    // 18.4 KB  (V transposed: VT[d][k])
    __shared__ short Plds[QT][PS];        // 18.4 KB  (wave-private row bands)

    const int tid  = threadIdx.x;
    const int wave = tid >> 6;
    const int lane = tid & 63;
    const int l15  = lane & 15;
    const int lg   = lane >> 4;           // 0..3

    const int bid = blockIdx.x;
    const int bh  = bid & 31;             // B*H = 32 (minor: same-bh neighbors)
    const int qt  = bid >> 5;             // 0..15
    const int q0  = qt * QT;

    const float* qb = q + (size_t)bh * S_LEN * D_DIM;
    const float* kb = k + (size_t)bh * S_LEN * D_DIM;
    const float* vb = v + (size_t)bh * S_LEN * D_DIM;
    float*       ob = out + (size_t)bh * S_LEN * D_DIM;

    const float scale = scale_p[0];

    // ---- Q fragments hoisted to registers, scale folded in: (Q*s)K^T = S*s
    // A-frag layout: lane holds A[l&15][(l>>4)*8 + e], e=0..7
    bf16x8 qa[2][4];
    {
        const int qrow = q0 + wave * 32;
        #pragma unroll
        for (int qf = 0; qf < 2; ++qf) {
            const float* qp = qb + (size_t)(qrow + qf*16 + l15) * D_DIM + lg * 8;
            #pragma unroll
            for (int dk = 0; dk < 4; ++dk) {
                f32x4 a = *(const f32x4*)(qp + dk*32);
                f32x4 b = *(const f32x4*)(qp + dk*32 + 4);
                bf16x8 t;
                t[0]=f2bf(a[0]*scale); t[1]=f2bf(a[1]*scale);
                t[2]=f2bf(a[2]*scale); t[3]=f2bf(a[3]*scale);
                t[4]=f2bf(b[0]*scale); t[5]=f2bf(b[1]*scale);
                t[6]=f2bf(b[2]*scale); t[7]=f2bf(b[3]*scale);
                qa[qf][dk] = t;
            }
        }
    }

    // ---- staging index map (whole block covers the 64x128 tile)
    const int kr = tid >> 4;              // 0..15 : K row within 16-row strip
    const int kc = tid & 15;              // 8-float chunk (col kc*8)
    const int vd = tid & 127;             // V column (d)
    const int vh = (tid >> 7) * 32;       // V k-half (0 or 32)

    // prefetch registers (tile t+1 in flight while tile t computes)
    f32x4 kreg[8];
    float vreg[32];

#define LOAD_TILE(T) do {                                                     \
    const float* kp_ = kb + (size_t)((T) * KT) * D_DIM;                       \
    _Pragma("unroll")                                                         \
    for (int p = 0; p < 4; ++p) {                                             \
        const float* rp_ = kp_ + (size_t)(p*16 + kr) * D_DIM + kc*8;          \
        kreg[2*p]   = *(const f32x4*)rp_;                                     \
        kreg[2*p+1] = *(const f32x4*)(rp_ + 4);                               \
    }                                                                         \
    const float* vp_ = vb + (size_t)((T) * KT + vh) * D_DIM + vd;             \
    _Pragma("unroll")                                                         \
    for (int j = 0; j < 32; ++j) vreg[j] = vp_[(size_t)j * D_DIM];            \
} while (0)

#define STORE_TILE() do {                                                     \
    _Pragma("unroll")                                                         \
    for (int p = 0; p < 4; ++p) {                                             \
        f32x4 a_ = kreg[2*p], b_ = kreg[2*p+1];                               \
        bf16x8 w_;                                                            \
        w_[0]=f2bf(a_[0]); w_[1]=f2bf(a_[1]); w_[2]=f2bf(a_[2]); w_[3]=f2bf(a_[3]); \
        w_[4]=f2bf(b_[0]); w_[5]=f2bf(b_[1]); w_[6]=f2bf(b_[2]); w_[7]=f2bf(b_[3]); \
        *(bf16x8*)&Klds[p*16 + kr][kc*8] = w_;                                \
    }                                                                         \
    _Pragma("unroll")                                                         \
    for (int c = 0; c < 4; ++c) {                                             \
        bf16x8 w_;                                                            \
        w_[0]=f2bf(vreg[c*8+0]); w_[1]=f2bf(vreg[c*8+1]);                     \
        w_[2]=f2bf(vreg[c*8+2]); w_[3]=f2bf(vreg[c*8+3]);                     \
        w_[4]=f2bf(vreg[c*8+4]); w_[5]=f2bf(vreg[c*8+5]);                     \
        w_[6]=f2bf(vreg[c*8+6]); w_[7]=f2bf(vreg[c*8+7]);                     \
        *(bf16x8*)&VTlds[vd][vh + c*8] = w_;                                  \
    }                                                                         \
} while (0)

    f32x4 oacc[2][8];
    #pragma unroll
    for (int i = 0; i < 2; ++i)
        #pragma unroll
        for (int j = 0; j < 8; ++j)
            oacc[i][j] = f32x4{0.f, 0.f, 0.f, 0.f};

    LOAD_TILE(0);   // prologue: tile 0 in flight

    for (int t = 0; t < NT; ++t) {
        // ---- write staged tile t into LDS (vmcnt drain happens here)
        STORE_TILE();
        __syncthreads();

        // ---- issue global loads for tile t+1 (latency hides under compute)
        LOAD_TILE((t + 1) & (NT - 1));

        // ---- S = (Q*s) K^T  (per wave: 32q x 64k, 2x4 16x16 fragments)
        f32x4 sacc[2][4];
        #pragma unroll
        for (int qf = 0; qf < 2; ++qf)
            #pragma unroll
            for (int kf = 0; kf < 4; ++kf)
                sacc[qf][kf] = f32x4{0.f, 0.f, 0.f, 0.f};

        #pragma unroll
        for (int dk = 0; dk < 4; ++dk) {
            #pragma unroll
            for (int kf = 0; kf < 4; ++kf) {
                bf16x8 bf = *(const bf16x8*)&Klds[kf*16 + l15][dk*32 + lg*8];
                #pragma unroll
                for (int qf = 0; qf < 2; ++qf)
                    sacc[qf][kf] = __builtin_amdgcn_mfma_f32_16x16x32_bf16(
                        qa[qf][dk], bf, sacc[qf][kf], 0, 0, 0);
            }
        }

        // ---- P = relu(S)^2 -> bf16 -> wave-private LDS rows
        #pragma unroll
        for (int qf = 0; qf < 2; ++qf) {
            #pragma unroll
            for (int kf = 0; kf < 4; ++kf) {
                f32x4 sv = sacc[qf][kf];
                #pragma unroll
                for (int e = 0; e < 4; ++e) {
                    float r = fmaxf(sv[e], 0.f);
                    Plds[wave*32 + qf*16 + lg*4 + e][kf*16 + l15] = f2bf(r * r);
                }
            }
        }
        // (no barrier: P rows are wave-private; same-wave DS ordering)

        // ---- O += P V   (per wave: 32q x 128d, k in 2 halves)
        #pragma unroll
        for (int ks = 0; ks < 2; ++ks) {
            bf16x8 pa[2];
            #pragma unroll
            for (int qf = 0; qf < 2; ++qf)
                pa[qf] = *(const bf16x8*)&Plds[wave*32 + qf*16 + l15][ks*32 + lg*8];
            #pragma unroll
            for (int df = 0; df < 8; ++df) {
                bf16x8 vf = *(const bf16x8*)&VTlds[df*16 + l15][ks*32 + lg*8];
                #pragma unroll
                for (int qf = 0; qf < 2; ++qf)
                    oacc[qf][df] = __builtin_amdgcn_mfma_f32_16x16x32_bf16(
                        pa[qf], vf, oacc[qf][df], 0, 0, 0);
            }
        }
        __syncthreads();   // protect Klds/VTlds before next tile's stores
    }

    // ---- epilogue: O fp32 stores (D-layout: row=(l>>4)*4+e, col=l&15)
    #pragma unroll
    for (int qf = 0; qf < 2; ++qf) {
        #pragma unroll
        for (int df = 0; df < 8; ++df) {
            f32x4 o = oacc[qf][df];
            const int row = q0 + wave*32 + qf*16 + lg*4;
            float* op = ob + (size_t)row * D_DIM + df*16 + l15;
            op[0*D_DIM] = o[0];
            op[1*D_DIM] = o[1];
            op[2*D_DIM] = o[2];
            op[3*D_DIM] = o[3];
        }
    }
}

extern "C" void kernel_launch(void* const* d_in, const int* in_sizes, int n_in,
                              void* d_out, int out_size, void* d_ws, size_t ws_size,
                              hipStream_t stream) {
    const float* q = (const float*)d_in[0];
    const float* k = (const float*)d_in[1];
    const float* v = (const float*)d_in[2];
    const float* scale = (const float*)d_in[3];
    float* out = (float*)d_out;

    const int blocks = (2 * 16) * (S_LEN / QT);   // 32 bh * 16 q-tiles = 512
    relu2_attn_kernel<<<dim3(blocks), dim3(256), 0, stream>>>(q, k, v, scale, out);
}

// Round 3
// 97.940 us; speedup vs baseline: 2.0539x; 1.0544x over previous
//
#include <hip/hip_runtime.h>
#include <hip/hip_bf16.h>
#include <stdint.h>

#define S_LEN 2048
#define D_DIM 128
#define QT 128          // q rows per block
#define KT 64           // k rows per tile
#define NT (S_LEN/KT)   // 32 tiles

typedef float  f32x4  __attribute__((ext_vector_type(4)));
typedef short  bf16x8 __attribute__((ext_vector_type(8)));
typedef short  bf16x4 __attribute__((ext_vector_type(4)));

__device__ __forceinline__ short f2bf(float f) {
    return __builtin_bit_cast(short, __float2bfloat16(f));
}

__device__ __forceinline__ void gload_lds16(const short* g, short* l) {
    __builtin_amdgcn_global_load_lds(
        (const __attribute__((address_space(1))) void*)g,
        (__attribute__((address_space(3))) void*)l,
        16, 0, 0);
}

// ---------------------------------------------------------------------------
// Pre-pass 1: K fp32 -> bf16, same row-major layout (flat elementwise copy).
// ---------------------------------------------------------------------------
__global__ __launch_bounds__(256)
void convert_k_kernel(const float* __restrict__ kin, short* __restrict__ kbf) {
    const size_t i = ((size_t)blockIdx.x * 256 + threadIdx.x) * 8;
    f32x4 a = *(const f32x4*)(kin + i);
    f32x4 c = *(const f32x4*)(kin + i + 4);
    bf16x8 t;
    t[0]=f2bf(a[0]); t[1]=f2bf(a[1]); t[2]=f2bf(a[2]); t[3]=f2bf(a[3]);
    t[4]=f2bf(c[0]); t[5]=f2bf(c[1]); t[6]=f2bf(c[2]); t[7]=f2bf(c[3]);
    *(bf16x8*)(kbf + i) = t;
}

// ---------------------------------------------------------------------------
// Pre-pass 2: V fp32 [bh][k][d] -> bf16 transposed VT [bh][d][S_LEN].
// Block = (bh, 16-wide d-group); LDS transpose per 128-k chunk.
// ---------------------------------------------------------------------------
__global__ __launch_bounds__(256)
void transpose_v_kernel(const float* __restrict__ vin, short* __restrict__ vt) {
    __shared__ short T[16 * 130];        // [d_local][k 128 + pad2]
    const int tid = threadIdx.x;
    const int blk = blockIdx.x;          // 256 = 32 bh * 8 dgroups
    const int bh  = blk >> 3;
    const int d0  = (blk & 7) * 16;
    const float* vb = vin + (size_t)bh * S_LEN * D_DIM;
    short* vtb = vt + (size_t)bh * (size_t)D_DIM * S_LEN;
    const int c4 = tid & 3;              // f32x4 chunk within 16-d group
    const int rr = tid >> 2;             // 0..63 : k row
    const int dl = tid >> 4;             // 0..15 : dump d row
    const int kc = tid & 15;             // 0..15 : dump k chunk (8 shorts)

    for (int kc0 = 0; kc0 < S_LEN; kc0 += 128) {
        #pragma unroll
        for (int h = 0; h < 2; ++h) {
            const int krow = kc0 + h*64 + rr;
            f32x4 a = *(const f32x4*)(vb + (size_t)krow * D_DIM + d0 + c4*4);
            #pragma unroll
            for (int j = 0; j < 4; ++j)
                T[(c4*4 + j)*130 + h*64 + rr] = f2bf(a[j]);
        }
        __syncthreads();
        int w0 = *(const int*)&T[dl*130 + kc*8 + 0];
        int w1 = *(const int*)&T[dl*130 + kc*8 + 2];
        int w2 = *(const int*)&T[dl*130 + kc*8 + 4];
        int w3 = *(const int*)&T[dl*130 + kc*8 + 6];
        int4 val = make_int4(w0, w1, w2, w3);
        *(int4*)(vtb + (size_t)(d0 + dl) * S_LEN + kc0 + kc*8) = val;
        __syncthreads();
    }
}

// ---------------------------------------------------------------------------
// Main kernel: bf16 K / VT staged via global_load_lds with pre-swizzled
// source addressing (XOR slot ^= row&7); swapped-QK so P writes are b64.
// LDS: Kbuf[2]16KB + Vbuf[2]16KB + P 16KB = 80KB -> 2 blocks/CU.
// ---------------------------------------------------------------------------
#define KOFF(B) ((B)*8192)
#define VOFF(B) (16384 + (B)*8192)
#define POFF 32768

__global__ __launch_bounds__(256, 2)
void relu2_attn_main(const float* __restrict__ q,
                     const short* __restrict__ kbf,
                     const short* __restrict__ vtbf,
                     const float* __restrict__ scale_p,
                     float* __restrict__ out) {
    __shared__ short lds[40960];   // 80 KB

    const int tid  = threadIdx.x;
    const int wave = tid >> 6;
    const int lane = tid & 63;
    const int l15  = lane & 15;
    const int lg   = lane >> 4;           // 0..3
    const int swz  = l15 & 7;

    const int bid = blockIdx.x;
    const int bh  = bid & 31;
    const int qt  = bid >> 5;
    const int q0  = qt * QT;

    const float* qb = q    + (size_t)bh * S_LEN * D_DIM;
    const short* kb = kbf  + (size_t)bh * S_LEN * D_DIM;
    const short* vt = vtbf + (size_t)bh * (size_t)D_DIM * S_LEN;
    float*       ob = out  + (size_t)bh * S_LEN * D_DIM;

    const float scale = scale_p[0];

    // Q fragments (scale folded); layout = lane holds Q[row=l15][d=lg*8+e]
    bf16x8 qa[2][4];
    {
        const int qrow = q0 + wave * 32;
        #pragma unroll
        for (int qf = 0; qf < 2; ++qf) {
            const float* qp = qb + (size_t)(qrow + qf*16 + l15) * D_DIM + lg * 8;
            #pragma unroll
            for (int dk = 0; dk < 4; ++dk) {
                f32x4 a = *(const f32x4*)(qp + dk*32);
                f32x4 c = *(const f32x4*)(qp + dk*32 + 4);
                bf16x8 t;
                t[0]=f2bf(a[0]*scale); t[1]=f2bf(a[1]*scale);
                t[2]=f2bf(a[2]*scale); t[3]=f2bf(a[3]*scale);
                t[4]=f2bf(c[0]*scale); t[5]=f2bf(c[1]*scale);
                t[6]=f2bf(c[2]*scale); t[7]=f2bf(c[3]*scale);
                qa[qf][dk] = t;
            }
        }
    }

    f32x4 oacc[2][8];
    #pragma unroll
    for (int i = 0; i < 2; ++i)
        #pragma unroll
        for (int j = 0; j < 8; ++j)
            oacc[i][j] = f32x4{0.f, 0.f, 0.f, 0.f};

// Stage tile T into buffer B. 16 chunks of 1KB each for K and V; chunk =
// p*4+wave (wave-uniform LDS base). Source address carries the XOR swizzle
// so linear global_load_lds produces the swizzled LDS layout.
#define STAGE(T, B) do {                                                      \
    const int k0_ = (T) * KT;                                                 \
    _Pragma("unroll")                                                         \
    for (int p_ = 0; p_ < 4; ++p_) {                                          \
        const int ch_ = p_*4 + wave;                                          \
        const int r_  = ch_*4 + (lane >> 4);      /* K row 0..63 */           \
        gload_lds16(kb + (((size_t)(k0_ + r_)) << 7)                          \
                       + (((lane & 15) ^ (r_ & 7)) << 3),                     \
                    &lds[KOFF(B) + ch_*512]);                                 \
        const int d_  = ch_*8 + (lane >> 3);      /* V row (d) 0..127 */      \
        gload_lds16(vt + (((size_t)d_) << 11) + k0_                           \
                       + (((lane & 7) ^ (d_ & 7)) << 3),                      \
                    &lds[VOFF(B) + ch_*512]);                                 \
    }                                                                         \
} while (0)

    STAGE(0, 0);

    for (int t = 0; t < NT; ++t) {
        const int b = t & 1;
        __syncthreads();                 // drains buf[b] loads (implicit vmcnt)
        if (t + 1 < NT) STAGE(t + 1, b ^ 1);

        // ---- S^T = K (Q*s)^T : per wave 2x4 16x16 frags (A=K, B=Q)
        f32x4 sacc[2][4];
        #pragma unroll
        for (int qf = 0; qf < 2; ++qf)
            #pragma unroll
            for (int kf = 0; kf < 4; ++kf)
                sacc[qf][kf] = f32x4{0.f, 0.f, 0.f, 0.f};

        #pragma unroll
        for (int dk = 0; dk < 4; ++dk) {
            #pragma unroll
            for (int kf = 0; kf < 4; ++kf) {
                const int krow = kf*16 + l15;
                bf16x8 af = *(const bf16x8*)
                    &lds[KOFF(b) + krow*128 + (((dk*4 + lg) ^ swz) << 3)];
                #pragma unroll
                for (int qf = 0; qf < 2; ++qf)
                    sacc[qf][kf] = __builtin_amdgcn_mfma_f32_16x16x32_bf16(
                        af, qa[qf][dk], sacc[qf][kf], 0, 0, 0);
            }
        }

        // ---- P = relu(S)^2 -> bf16: lane holds P[q=l15][k=kf*16+lg*4+e]
        //      -> one ds_write_b64 per (qf,kf), swizzled
        #pragma unroll
        for (int qf = 0; qf < 2; ++qf) {
            const int qrow = wave*32 + qf*16 + l15;
            #pragma unroll
            for (int kf = 0; kf < 4; ++kf) {
                f32x4 sv = sacc[qf][kf];
                bf16x4 w;
                #pragma unroll
                for (int e = 0; e < 4; ++e) {
                    float r0 = fmaxf(sv[e], 0.f);
                    w[e] = f2bf(r0 * r0);
                }
                *(bf16x4*)&lds[POFF + qrow*64 + ((kf*16 + lg*4) ^ (swz << 3))] = w;
            }
        }

        // ---- O += P V  (A=P from LDS, B=VT from LDS)
        #pragma unroll
        for (int ks = 0; ks < 2; ++ks) {
            bf16x8 pa[2];
            #pragma unroll
            for (int qf = 0; qf < 2; ++qf) {
                const int qrow = wave*32 + qf*16 + l15;
                pa[qf] = *(const bf16x8*)
                    &lds[POFF + qrow*64 + ((ks*32 + lg*8) ^ (swz << 3))];
            }
            #pragma unroll
            for (int df = 0; df < 8; ++df) {
                const int drow = df*16 + l15;
                bf16x8 vf = *(const bf16x8*)
                    &lds[VOFF(b) + drow*64 + (((ks*4 + lg) ^ swz) << 3)];
                #pragma unroll
                for (int qf = 0; qf < 2; ++qf)
                    oacc[qf][df] = __builtin_amdgcn_mfma_f32_16x16x32_bf16(
                        pa[qf], vf, oacc[qf][df], 0, 0, 0);
            }
        }
    }

    // ---- epilogue: O fp32 (D-layout: row=lg*4+e, col=l15)
    #pragma unroll
    for (int qf = 0; qf < 2; ++qf) {
        #pragma unroll
        for (int df = 0; df < 8; ++df) {
            f32x4 o = oacc[qf][df];
            const int row = q0 + wave*32 + qf*16 + lg*4;
            float* op = ob + (size_t)row * D_DIM + df*16 + l15;
            op[0*D_DIM] = o[0];
            op[1*D_DIM] = o[1];
            op[2*D_DIM] = o[2];
            op[3*D_DIM] = o[3];
        }
    }
}

// ---------------------------------------------------------------------------
// Fallback (proven R2 kernel) if ws is too small for the bf16 side buffers.
// ---------------------------------------------------------------------------
#define KS 136
#define VS 72
#define PS 72

__global__ __launch_bounds__(256, 2)
void relu2_attn_fallback(const float* __restrict__ q,
                         const float* __restrict__ k,
                         const float* __restrict__ v,
                         const float* __restrict__ scale_p,
                         float* __restrict__ out) {
    __shared__ short Klds[KT][KS];
    __shared__ short VTlds[D_DIM][VS];
    __shared__ short Plds[QT][PS];

    const int tid  = threadIdx.x;
    const int wave = tid >> 6;
    const int lane = tid & 63;
    const int l15  = lane & 15;
    const int lg   = lane >> 4;

    const int bid = blockIdx.x;
    const int bh  = bid & 31;
    const int qt  = bid >> 5;
    const int q0  = qt * QT;

    const float* qb = q + (size_t)bh * S_LEN * D_DIM;
    const float* kb = k + (size_t)bh * S_LEN * D_DIM;
    const float* vb = v + (size_t)bh * S_LEN * D_DIM;
    float*       ob = out + (size_t)bh * S_LEN * D_DIM;

    const float scale = scale_p[0];

    bf16x8 qa[2][4];
    {
        const int qrow = q0 + wave * 32;
        #pragma unroll
        for (int qf = 0; qf < 2; ++qf) {
            const float* qp = qb + (size_t)(qrow + qf*16 + l15) * D_DIM + lg * 8;
            #pragma unroll
            for (int dk = 0; dk < 4; ++dk) {
                f32x4 a = *(const f32x4*)(qp + dk*32);
                f32x4 c = *(const f32x4*)(qp + dk*32 + 4);
                bf16x8 t;
                t[0]=f2bf(a[0]*scale); t[1]=f2bf(a[1]*scale);
                t[2]=f2bf(a[2]*scale); t[3]=f2bf(a[3]*scale);
                t[4]=f2bf(c[0]*scale); t[5]=f2bf(c[1]*scale);
                t[6]=f2bf(c[2]*scale); t[7]=f2bf(c[3]*scale);
                qa[qf][dk] = t;
            }
        }
    }

    const int kr = tid >> 4;
    const int kc = tid & 15;
    const int vd = tid & 127;
    const int vh = (tid >> 7) * 32;

    f32x4 kreg[8];
    float vreg[32];

#define FLOAD_TILE(T) do {                                                    \
    const float* kp_ = kb + (size_t)((T) * KT) * D_DIM;                       \
    _Pragma("unroll")                                                         \
    for (int p = 0; p < 4; ++p) {                                             \
        const float* rp_ = kp_ + (size_t)(p*16 + kr) * D_DIM + kc*8;          \
        kreg[2*p]   = *(const f32x4*)rp_;                                     \
        kreg[2*p+1] = *(const f32x4*)(rp_ + 4);                               \
    }                                                                         \
    const float* vp_ = vb + (size_t)((T) * KT + vh) * D_DIM + vd;             \
    _Pragma("unroll")                                                         \
    for (int j = 0; j < 32; ++j) vreg[j] = vp_[(size_t)j * D_DIM];            \
} while (0)

#define FSTORE_TILE() do {                                                    \
    _Pragma("unroll")                                                         \
    for (int p = 0; p < 4; ++p) {                                             \
        f32x4 a_ = kreg[2*p], b_ = kreg[2*p+1];                               \
        bf16x8 w_;                                                            \
        w_[0]=f2bf(a_[0]); w_[1]=f2bf(a_[1]); w_[2]=f2bf(a_[2]); w_[3]=f2bf(a_[3]); \
        w_[4]=f2bf(b_[0]); w_[5]=f2bf(b_[1]); w_[6]=f2bf(b_[2]); w_[7]=f2bf(b_[3]); \
        *(bf16x8*)&Klds[p*16 + kr][kc*8] = w_;                                \
    }                                                                         \
    _Pragma("unroll")                                                         \
    for (int c = 0; c < 4; ++c) {                                             \
        bf16x8 w_;                                                            \
        w_[0]=f2bf(vreg[c*8+0]); w_[1]=f2bf(vreg[c*8+1]);                     \
        w_[2]=f2bf(vreg[c*8+2]); w_[3]=f2bf(vreg[c*8+3]);                     \
        w_[4]=f2bf(vreg[c*8+4]); w_[5]=f2bf(vreg[c*8+5]);                     \
        w_[6]=f2bf(vreg[c*8+6]); w_[7]=f2bf(vreg[c*8+7]);                     \
        *(bf16x8*)&VTlds[vd][vh + c*8] = w_;                                  \
    }                                                                         \
} while (0)

    f32x4 oacc[2][8];
    #pragma unroll
    for (int i = 0; i < 2; ++i)
        #pragma unroll
        for (int j = 0; j < 8; ++j)
            oacc[i][j] = f32x4{0.f, 0.f, 0.f, 0.f};

    FLOAD_TILE(0);

    for (int t = 0; t < NT; ++t) {
        FSTORE_TILE();
        __syncthreads();
        FLOAD_TILE((t + 1) & (NT - 1));

        f32x4 sacc[2][4];
        #pragma unroll
        for (int qf = 0; qf < 2; ++qf)
            #pragma unroll
            for (int kf = 0; kf < 4; ++kf)
                sacc[qf][kf] = f32x4{0.f, 0.f, 0.f, 0.f};

        #pragma unroll
        for (int dk = 0; dk < 4; ++dk) {
            #pragma unroll
            for (int kf = 0; kf < 4; ++kf) {
                bf16x8 bf = *(const bf16x8*)&Klds[kf*16 + l15][dk*32 + lg*8];
                #pragma unroll
                for (int qf = 0; qf < 2; ++qf)
                    sacc[qf][kf] = __builtin_amdgcn_mfma_f32_16x16x32_bf16(
                        qa[qf][dk], bf, sacc[qf][kf], 0, 0, 0);
            }
        }

        #pragma unroll
        for (int qf = 0; qf < 2; ++qf) {
            #pragma unroll
            for (int kf = 0; kf < 4; ++kf) {
                f32x4 sv = sacc[qf][kf];
                #pragma unroll
                for (int e = 0; e < 4; ++e) {
                    float r = fmaxf(sv[e], 0.f);
                    Plds[wave*32 + qf*16 + lg*4 + e][kf*16 + l15] = f2bf(r * r);
                }
            }
        }

        #pragma unroll
        for (int ks = 0; ks < 2; ++ks) {
            bf16x8 pa[2];
            #pragma unroll
            for (int qf = 0; qf < 2; ++qf)
                pa[qf] = *(const bf16x8*)&Plds[wave*32 + qf*16 + l15][ks*32 + lg*8];
            #pragma unroll
            for (int df = 0; df < 8; ++df) {
                bf16x8 vf = *(const bf16x8*)&VTlds[df*16 + l15][ks*32 + lg*8];
                #pragma unroll
                for (int qf = 0; qf < 2; ++qf)
                    oacc[qf][df] = __builtin_amdgcn_mfma_f32_16x16x32_bf16(
                        pa[qf], vf, oacc[qf][df], 0, 0, 0);
            }
        }
        __syncthreads();
    }

    #pragma unroll
    for (int qf = 0; qf < 2; ++qf) {
        #pragma unroll
        for (int df = 0; df < 8; ++df) {
            f32x4 o = oacc[qf][df];
            const int row = q0 + wave*32 + qf*16 + lg*4;
            float* op = ob + (size_t)row * D_DIM + df*16 + l15;
            op[0*D_DIM] = o[0];
            op[1*D_DIM] = o[1];
            op[2*D_DIM] = o[2];
            op[3*D_DIM] = o[3];
        }
    }
}

extern "C" void kernel_launch(void* const* d_in, const int* in_sizes, int n_in,
                              void* d_out, int out_size, void* d_ws, size_t ws_size,
                              hipStream_t stream) {
    const float* q = (const float*)d_in[0];
    const float* k = (const float*)d_in[1];
    const float* v = (const float*)d_in[2];
    const float* scale = (const float*)d_in[3];
    float* out = (float*)d_out;

    const size_t elems = (size_t)2 * 16 * S_LEN * D_DIM;   // 8.39M per tensor
    const size_t need  = elems * 2 * 2;                    // K + VT bf16 bytes

    if (ws_size >= need) {
        short* kbf = (short*)d_ws;
        short* vtb = (short*)d_ws + elems;
        convert_k_kernel<<<dim3((int)(elems / (256 * 8))), dim3(256), 0, stream>>>(k, kbf);
        transpose_v_kernel<<<dim3(256), dim3(256), 0, stream>>>(v, vtb);
        relu2_attn_main<<<dim3(512), dim3(256), 0, stream>>>(q, kbf, vtb, scale, out);
    } else {
        relu2_attn_fallback<<<dim3(512), dim3(256), 0, stream>>>(q, k, v, scale, out);
    }
}

// Round 4
// 97.796 us; speedup vs baseline: 2.0569x; 1.0015x over previous
//
#include <hip/hip_runtime.h>
#include <hip/hip_bf16.h>
#include <stdint.h>

#define S_LEN 2048
#define D_DIM 128
#define QT 128          // q rows per block (4 waves x 32)
#define KT 64           // k rows per tile
#define NT (S_LEN/KT)   // 32 tiles

typedef float  f32x4  __attribute__((ext_vector_type(4)));
typedef float  f32x16 __attribute__((ext_vector_type(16)));
typedef short  bf16x8 __attribute__((ext_vector_type(8)));
typedef short  bf16x4 __attribute__((ext_vector_type(4)));
typedef unsigned int uintx4 __attribute__((ext_vector_type(4)));

__device__ __forceinline__ short f2bf(float f) {
    return __builtin_bit_cast(short, __float2bfloat16(f));
}

__device__ __forceinline__ unsigned int pk2(float lo, float hi) {
    unsigned int d;
    asm("v_cvt_pk_bf16_f32 %0, %1, %2" : "=v"(d) : "v"(lo), "v"(hi));
    return d;
}

__device__ __forceinline__ void gload_lds16(const short* g, short* l) {
    __builtin_amdgcn_global_load_lds(
        (const __attribute__((address_space(1))) void*)g,
        (__attribute__((address_space(3))) void*)l,
        16, 0, 0);
}

// ---------------------------------------------------------------------------
// Pre-pass 1: K fp32 -> bf16 row-major copy.
// ---------------------------------------------------------------------------
__global__ __launch_bounds__(256)
void convert_k_kernel(const float* __restrict__ kin, short* __restrict__ kbf) {
    const size_t i = ((size_t)blockIdx.x * 256 + threadIdx.x) * 8;
    f32x4 a = *(const f32x4*)(kin + i);
    f32x4 c = *(const f32x4*)(kin + i + 4);
    bf16x8 t;
    t[0]=f2bf(a[0]); t[1]=f2bf(a[1]); t[2]=f2bf(a[2]); t[3]=f2bf(a[3]);
    t[4]=f2bf(c[0]); t[5]=f2bf(c[1]); t[6]=f2bf(c[2]); t[7]=f2bf(c[3]);
    *(bf16x8*)(kbf + i) = t;
}

// ---------------------------------------------------------------------------
// Pre-pass 2: V fp32 [bh][k][d] -> bf16 transposed VT [bh][d][S_LEN].
// ---------------------------------------------------------------------------
__global__ __launch_bounds__(256)
void transpose_v_kernel(const float* __restrict__ vin, short* __restrict__ vt) {
    __shared__ short T[16 * 130];
    const int tid = threadIdx.x;
    const int blk = blockIdx.x;          // 256 = 32 bh * 8 dgroups
    const int bh  = blk >> 3;
    const int d0  = (blk & 7) * 16;
    const float* vb = vin + (size_t)bh * S_LEN * D_DIM;
    short* vtb = vt + (size_t)bh * (size_t)D_DIM * S_LEN;
    const int c4 = tid & 3;
    const int rr = tid >> 2;
    const int dl = tid >> 4;
    const int kc = tid & 15;

    for (int kc0 = 0; kc0 < S_LEN; kc0 += 128) {
        #pragma unroll
        for (int h = 0; h < 2; ++h) {
            const int krow = kc0 + h*64 + rr;
            f32x4 a = *(const f32x4*)(vb + (size_t)krow * D_DIM + d0 + c4*4);
            #pragma unroll
            for (int j = 0; j < 4; ++j)
                T[(c4*4 + j)*130 + h*64 + rr] = f2bf(a[j]);
        }
        __syncthreads();
        int w0 = *(const int*)&T[dl*130 + kc*8 + 0];
        int w1 = *(const int*)&T[dl*130 + kc*8 + 2];
        int w2 = *(const int*)&T[dl*130 + kc*8 + 4];
        int w3 = *(const int*)&T[dl*130 + kc*8 + 6];
        int4 val = make_int4(w0, w1, w2, w3);
        *(int4*)(vtb + (size_t)(d0 + dl) * S_LEN + kc0 + kc*8) = val;
        __syncthreads();
    }
}

// ---------------------------------------------------------------------------
// Main kernel: 32x32x16 MFMA, swapped QK^T, in-register P via
// cvt_pk_bf16 + v_permlane32_swap (no P LDS round trip).
// LDS: K dbuf 2x16KB @ [0,32KB) + VT dbuf 2x16KB @ [32KB,64KB).
// XOR-swizzled slots (slot ^= row&7), source-pre-swizzled global_load_lds.
// ---------------------------------------------------------------------------
__global__ __launch_bounds__(256, 2)
void relu2_attn_main(const float* __restrict__ q,
                     const short* __restrict__ kbf,
                     const short* __restrict__ vtbf,
                     const float* __restrict__ scale_p,
                     float* __restrict__ out) {
    __shared__ __align__(16) char lds[65536];

    const int tid  = threadIdx.x;
    const int wave = tid >> 6;
    const int lane = tid & 63;
    const int l31  = lane & 31;
    const int hi   = lane >> 5;          // 0/1
    const int swz  = l31 & 7;

    const int bid = blockIdx.x;
    const int bh  = bid & 31;
    const int qt  = bid >> 5;
    const int q0  = qt * QT;

    const float* qb = q    + (size_t)bh * S_LEN * D_DIM;
    const short* kb = kbf  + (size_t)bh * S_LEN * D_DIM;
    const short* vt = vtbf + (size_t)bh * (size_t)D_DIM * S_LEN;
    float*       ob = out  + (size_t)bh * S_LEN * D_DIM;

    const float scale = scale_p[0];

    // per-lane XOR-folded base byte offsets (slot = c ^ hi ^ swz)
    const int KB = l31*256 + ((hi ^ swz) << 4);          // K region @ 0
    const int VB = 32768 + l31*128 + ((hi ^ swz) << 4);  // V region @ 32KB

    // ---- Q fragments: lane holds Q[q = wave*32+l31][d = dk*16 + hi*8 + e]
    bf16x8 qa[8];
    {
        const int qrow = q0 + wave*32 + l31;
        const float* qp = qb + (size_t)qrow * D_DIM + hi*8;
        #pragma unroll
        for (int dk = 0; dk < 8; ++dk) {
            f32x4 a = *(const f32x4*)(qp + dk*16);
            f32x4 c = *(const f32x4*)(qp + dk*16 + 4);
            bf16x8 t;
            t[0]=f2bf(a[0]*scale); t[1]=f2bf(a[1]*scale);
            t[2]=f2bf(a[2]*scale); t[3]=f2bf(a[3]*scale);
            t[4]=f2bf(c[0]*scale); t[5]=f2bf(c[1]*scale);
            t[6]=f2bf(c[2]*scale); t[7]=f2bf(c[3]*scale);
            qa[dk] = t;
        }
    }

    f32x16 oacc[4];
    #pragma unroll
    for (int df = 0; df < 4; ++df) oacc[df] = {};

// Stage tile T into buffer B (16 K-chunks + 16 V-chunks of 1KB, 4 per wave).
// Global source carries the XOR swizzle; LDS dest is linear (wave-uniform).
#define STAGE(T, B) do {                                                      \
    const int k0_ = (T) * KT;                                                 \
    _Pragma("unroll")                                                         \
    for (int p_ = 0; p_ < 4; ++p_) {                                          \
        const int ch_ = p_*4 + wave;                                          \
        const int r_  = ch_*4 + (lane >> 4);      /* K row 0..63 */           \
        gload_lds16(kb + (((size_t)(k0_ + r_)) << 7)                          \
                       + (((lane & 15) ^ (r_ & 7)) << 3),                     \
                    (short*)(lds + (B)*16384 + ch_*1024));                    \
        const int d_  = ch_*8 + (lane >> 3);      /* VT row (d) 0..127 */     \
        gload_lds16(vt + (((size_t)d_) << 11) + k0_                           \
                       + (((lane & 7) ^ (d_ & 7)) << 3),                      \
                    (short*)(lds + 32768 + (B)*16384 + ch_*1024));            \
    }                                                                         \
} while (0)

// One K-tile of compute from buffer BUF (compile-time 0/1).
#define TILE_COMPUTE(BUF) do {                                                \
    f32x16 s0 = {}, s1 = {};                                                  \
    __builtin_amdgcn_s_setprio(1);                                            \
    _Pragma("unroll")                                                         \
    for (int dk = 0; dk < 8; ++dk) {                                          \
        bf16x8 a0 = *(const bf16x8*)(lds + ((KB ^ (dk<<5)) | ((BUF)<<14)));   \
        bf16x8 a1 = *(const bf16x8*)(lds + ((KB ^ (dk<<5)) | (1<<13) | ((BUF)<<14))); \
        s0 = __builtin_amdgcn_mfma_f32_32x32x16_bf16(a0, qa[dk], s0, 0, 0, 0);\
        s1 = __builtin_amdgcn_mfma_f32_32x32x16_bf16(a1, qa[dk], s1, 0, 0, 0);\
    }                                                                         \
    __builtin_amdgcn_s_setprio(0);                                            \
    /* P = relu(S)^2 -> bf16 A-frags via cvt_pk + permlane32_swap */          \
    bf16x8 pa[4];                                                             \
    _Pragma("unroll")                                                         \
    for (int kf = 0; kf < 2; ++kf) {                                          \
        const f32x16 sv = kf ? s1 : s0;                                       \
        float pr[16];                                                         \
        _Pragma("unroll")                                                     \
        for (int r = 0; r < 16; ++r) {                                        \
            float m_ = fmaxf(sv[r], 0.f); pr[r] = m_ * m_;                    \
        }                                                                     \
        _Pragma("unroll")                                                     \
        for (int t2 = 0; t2 < 2; ++t2) {                                      \
            unsigned int X  = pk2(pr[8*t2+0], pr[8*t2+1]);                    \
            unsigned int Y  = pk2(pr[8*t2+4], pr[8*t2+5]);                    \
            unsigned int X2 = pk2(pr[8*t2+2], pr[8*t2+3]);                    \
            unsigned int Y2 = pk2(pr[8*t2+6], pr[8*t2+7]);                    \
            asm volatile("v_permlane32_swap_b32 %0, %1" : "+v"(X),  "+v"(Y)); \
            asm volatile("v_permlane32_swap_b32 %0, %1" : "+v"(X2), "+v"(Y2));\
            pa[kf*2 + t2] = __builtin_bit_cast(bf16x8, (uintx4){X, X2, Y, Y2});\
        }                                                                     \
    }                                                                         \
    __builtin_amdgcn_s_setprio(1);                                            \
    _Pragma("unroll")                                                         \
    for (int s_ = 0; s_ < 4; ++s_) {                                          \
        _Pragma("unroll")                                                     \
        for (int df = 0; df < 4; ++df) {                                      \
            bf16x8 vf = *(const bf16x8*)(lds + ((VB ^ (s_<<5)) | (df<<12) | ((BUF)<<14))); \
            oacc[df] = __builtin_amdgcn_mfma_f32_32x32x16_bf16(pa[s_], vf, oacc[df], 0, 0, 0); \
        }                                                                     \
    }                                                                         \
    __builtin_amdgcn_s_setprio(0);                                            \
} while (0)

    STAGE(0, 0);

    #pragma unroll 1
    for (int p = 0; p < NT/2; ++p) {
        __syncthreads();                  // buf0 loads landed; buf1 free
        STAGE(2*p + 1, 1);
        TILE_COMPUTE(0);
        __syncthreads();                  // buf1 loads landed; buf0 free
        STAGE((2*p + 2) & (NT - 1), 0);   // last iter: harmless reload of t=0
        TILE_COMPUTE(1);
    }

    // ---- epilogue: O[q = rg*8 + hi*4 + e][d = df*32 + l31]
    #pragma unroll
    for (int df = 0; df < 4; ++df) {
        #pragma unroll
        for (int rg = 0; rg < 4; ++rg) {
            #pragma unroll
            for (int e = 0; e < 4; ++e) {
                const int row = q0 + wave*32 + rg*8 + hi*4 + e;
                ob[(size_t)row * D_DIM + df*32 + l31] = oacc[df][rg*4 + e];
            }
        }
    }
}

// ---------------------------------------------------------------------------
// Fallback (proven R2 kernel) if ws is too small for the bf16 side buffers.
// ---------------------------------------------------------------------------
#define KS 136
#define VS 72
#define PS 72

__global__ __launch_bounds__(256, 2)
void relu2_attn_fallback(const float* __restrict__ q,
                         const float* __restrict__ k,
                         const float* __restrict__ v,
                         const float* __restrict__ scale_p,
                         float* __restrict__ out) {
    __shared__ short Klds[KT][KS];
    __shared__ short VTlds[D_DIM][VS];
    __shared__ short Plds[QT][PS];

    const int tid  = threadIdx.x;
    const int wave = tid >> 6;
    const int lane = tid & 63;
    const int l15  = lane & 15;
    const int lg   = lane >> 4;

    const int bid = blockIdx.x;
    const int bh  = bid & 31;
    const int qt  = bid >> 5;
    const int q0  = qt * QT;

    const float* qb = q + (size_t)bh * S_LEN * D_DIM;
    const float* kb = k + (size_t)bh * S_LEN * D_DIM;
    const float* vb = v + (size_t)bh * S_LEN * D_DIM;
    float*       ob = out + (size_t)bh * S_LEN * D_DIM;

    const float scale = scale_p[0];

    bf16x8 qa[2][4];
    {
        const int qrow = q0 + wave * 32;
        #pragma unroll
        for (int qf = 0; qf < 2; ++qf) {
            const float* qp = qb + (size_t)(qrow + qf*16 + l15) * D_DIM + lg * 8;
            #pragma unroll
            for (int dk = 0; dk < 4; ++dk) {
                f32x4 a = *(const f32x4*)(qp + dk*32);
                f32x4 c = *(const f32x4*)(qp + dk*32 + 4);
                bf16x8 t;
                t[0]=f2bf(a[0]*scale); t[1]=f2bf(a[1]*scale);
                t[2]=f2bf(a[2]*scale); t[3]=f2bf(a[3]*scale);
                t[4]=f2bf(c[0]*scale); t[5]=f2bf(c[1]*scale);
                t[6]=f2bf(c[2]*scale); t[7]=f2bf(c[3]*scale);
                qa[qf][dk] = t;
            }
        }
    }

    const int kr = tid >> 4;
    const int kc = tid & 15;
    const int vd = tid & 127;
    const int vh = (tid >> 7) * 32;

    f32x4 kreg[8];
    float vreg[32];

#define FLOAD_TILE(T) do {                                                    \
    const float* kp_ = kb + (size_t)((T) * KT) * D_DIM;                       \
    _Pragma("unroll")                                                         \
    for (int p = 0; p < 4; ++p) {                                             \
        const float* rp_ = kp_ + (size_t)(p*16 + kr) * D_DIM + kc*8;          \
        kreg[2*p]   = *(const f32x4*)rp_;                                     \
        kreg[2*p+1] = *(const f32x4*)(rp_ + 4);                               \
    }                                                                         \
    const float* vp_ = vb + (size_t)((T) * KT + vh) * D_DIM + vd;             \
    _Pragma("unroll")                                                         \
    for (int j = 0; j < 32; ++j) vreg[j] = vp_[(size_t)j * D_DIM];            \
} while (0)

#define FSTORE_TILE() do {                                                    \
    _Pragma("unroll")                                                         \
    for (int p = 0; p < 4; ++p) {                                             \
        f32x4 a_ = kreg[2*p], b_ = kreg[2*p+1];                               \
        bf16x8 w_;                                                            \
        w_[0]=f2bf(a_[0]); w_[1]=f2bf(a_[1]); w_[2]=f2bf(a_[2]); w_[3]=f2bf(a_[3]); \
        w_[4]=f2bf(b_[0]); w_[5]=f2bf(b_[1]); w_[6]=f2bf(b_[2]); w_[7]=f2bf(b_[3]); \
        *(bf16x8*)&Klds[p*16 + kr][kc*8] = w_;                                \
    }                                                                         \
    _Pragma("unroll")                                                         \
    for (int c = 0; c < 4; ++c) {                                             \
        bf16x8 w_;                                                            \
        w_[0]=f2bf(vreg[c*8+0]); w_[1]=f2bf(vreg[c*8+1]);                     \
        w_[2]=f2bf(vreg[c*8+2]); w_[3]=f2bf(vreg[c*8+3]);                     \
        w_[4]=f2bf(vreg[c*8+4]); w_[5]=f2bf(vreg[c*8+5]);                     \
        w_[6]=f2bf(vreg[c*8+6]); w_[7]=f2bf(vreg[c*8+7]);                     \
        *(bf16x8*)&VTlds[vd][vh + c*8] = w_;                                  \
    }                                                                         \
} while (0)

    f32x4 oacc[2][8];
    #pragma unroll
    for (int i = 0; i < 2; ++i)
        #pragma unroll
        for (int j = 0; j < 8; ++j)
            oacc[i][j] = f32x4{0.f, 0.f, 0.f, 0.f};

    FLOAD_TILE(0);

    for (int t = 0; t < NT; ++t) {
        FSTORE_TILE();
        __syncthreads();
        FLOAD_TILE((t + 1) & (NT - 1));

        f32x4 sacc[2][4];
        #pragma unroll
        for (int qf = 0; qf < 2; ++qf)
            #pragma unroll
            for (int kf = 0; kf < 4; ++kf)
                sacc[qf][kf] = f32x4{0.f, 0.f, 0.f, 0.f};

        #pragma unroll
        for (int dk = 0; dk < 4; ++dk) {
            #pragma unroll
            for (int kf = 0; kf < 4; ++kf) {
                bf16x8 bf = *(const bf16x8*)&Klds[kf*16 + l15][dk*32 + lg*8];
                #pragma unroll
                for (int qf = 0; qf < 2; ++qf)
                    sacc[qf][kf] = __builtin_amdgcn_mfma_f32_16x16x32_bf16(
                        qa[qf][dk], bf, sacc[qf][kf], 0, 0, 0);
            }
        }

        #pragma unroll
        for (int qf = 0; qf < 2; ++qf) {
            #pragma unroll
            for (int kf = 0; kf < 4; ++kf) {
                f32x4 sv = sacc[qf][kf];
                #pragma unroll
                for (int e = 0; e < 4; ++e) {
                    float r = fmaxf(sv[e], 0.f);
                    Plds[wave*32 + qf*16 + lg*4 + e][kf*16 + l15] = f2bf(r * r);
                }
            }
        }

        #pragma unroll
        for (int ks = 0; ks < 2; ++ks) {
            bf16x8 pa[2];
            #pragma unroll
            for (int qf = 0; qf < 2; ++qf)
                pa[qf] = *(const bf16x8*)&Plds[wave*32 + qf*16 + l15][ks*32 + lg*8];
            #pragma unroll
            for (int df = 0; df < 8; ++df) {
                bf16x8 vf = *(const bf16x8*)&VTlds[df*16 + l15][ks*32 + lg*8];
                #pragma unroll
                for (int qf = 0; qf < 2; ++qf)
                    oacc[qf][df] = __builtin_amdgcn_mfma_f32_16x16x32_bf16(
                        pa[qf], vf, oacc[qf][df], 0, 0, 0);
            }
        }
        __syncthreads();
    }

    #pragma unroll
    for (int qf = 0; qf < 2; ++qf) {
        #pragma unroll
        for (int df = 0; df < 8; ++df) {
            f32x4 o = oacc[qf][df];
            const int row = q0 + wave*32 + qf*16 + lg*4;
            float* op = ob + (size_t)row * D_DIM + df*16 + l15;
            op[0*D_DIM] = o[0];
            op[1*D_DIM] = o[1];
            op[2*D_DIM] = o[2];
            op[3*D_DIM] = o[3];
        }
    }
}

extern "C" void kernel_launch(void* const* d_in, const int* in_sizes, int n_in,
                              void* d_out, int out_size, void* d_ws, size_t ws_size,
                              hipStream_t stream) {
    const float* q = (const float*)d_in[0];
    const float* k = (const float*)d_in[1];
    const float* v = (const float*)d_in[2];
    const float* scale = (const float*)d_in[3];
    float* out = (float*)d_out;

    const size_t elems = (size_t)2 * 16 * S_LEN * D_DIM;   // 8.39M per tensor
    const size_t need  = elems * 2 * 2;                    // K + VT bf16 bytes

    if (ws_size >= need) {
        short* kbf = (short*)d_ws;
        short* vtb = (short*)d_ws + elems;
        convert_k_kernel<<<dim3((int)(elems / (256 * 8))), dim3(256), 0, stream>>>(k, kbf);
        transpose_v_kernel<<<dim3(256), dim3(256), 0, stream>>>(v, vtb);
        relu2_attn_main<<<dim3(512), dim3(256), 0, stream>>>(q, kbf, vtb, scale, out);
    } else {
        relu2_attn_fallback<<<dim3(512), dim3(256), 0, stream>>>(q, k, v, scale, out);
    }
}